// Round 1
// baseline (2117.605 us; speedup 1.0000x reference)
//
#include <hip/hip_runtime.h>
#include <math.h>

// Problem constants
#define BB    2
#define CC    256
#define FF    16
#define NN    4096      // 64*64 spatial
#define BF    32        // BB*FF
#define HEADS 8
#define DH    32
#define HID   256
#define NS    8         // n-range splits in K1
#define TN    32        // n tile width
#define SCALEF 0.17677669529663687f   // 32^-0.5

// ws layout (in floats)
#define WT_OFF    0                         // wT[256][768]
#define PARTC_OFF (256*768)                 // partC[BF][NS][256][32]
#define PARTZ_OFF (PARTC_OFF + BF*NS*256*32)// partz[BF][NS][256]
#define MT_OFF    (PARTZ_OFF + BF*NS*256)   // Mt[BF][256][256]
// total = 196608 + 2097152 + 65536 + 2097152 floats = ~17 MiB

// K0: transpose w_qkv [768][256] -> wT[256][768] so GEMM weight loads are lane-coalesced
__global__ __launch_bounds__(256) void k0_transpose(const float* __restrict__ wqkv,
                                                    float* __restrict__ wT) {
    int idx = blockIdx.x * 256 + threadIdx.x;   // 0 .. 768*256
    int o = idx >> 8;
    int c = idx & 255;
    wT[c * 768 + o] = wqkv[idx];
}

// K1: per (bf, n-split): compute k,v = W_{k,v} @ X on n-tiles; accumulate
// partC[hd][e] = sum_n exp(k[hd,n]) * v[(h,e),n]  and  partz[hd] = sum_n exp(k[hd,n])
__global__ __launch_bounds__(512) void k1_context(const float* __restrict__ x,
                                                  const float* __restrict__ wT,
                                                  float* __restrict__ partC,
                                                  float* __restrict__ partz) {
    const int ns = blockIdx.x;      // 0..NS-1
    const int bf = blockIdx.y;      // 0..BF-1
    const int b = bf >> 4, f = bf & 15;
    const float* xbase = x + (size_t)b * (CC * FF * NN) + (size_t)f * NN;
    const int t = threadIdx.x;
    const int r = t & 255;          // row (h*32+d) for k-half, (h*32+e) for v-half
    const int half = t >> 8;        // 0: k rows, 1: v rows
    const int h = r >> 5;

    __shared__ float xs[256][36];
    __shared__ float vs[256][36];
    __shared__ float ps[256][36];

    float C[16];
#pragma unroll
    for (int e = 0; e < 16; ++e) C[e] = 0.f;
    float zacc = 0.f;

    const int wcol = (half ? 512 : 256) + r;   // w_qkv row index (k block / v block)

    for (int tile = 0; tile < (NN / NS) / TN; ++tile) {
        const int n0 = ns * (NN / NS) + tile * TN;
        // ---- stage X tile [256 c][32 n] ----
#pragma unroll
        for (int kk = 0; kk < 16; ++kk) {
            int idx = t + kk * 512;
            int c = idx >> 5, j = idx & 31;
            xs[c][j] = xbase[(size_t)c * (FF * NN) + n0 + j];
        }
        __syncthreads();
        // ---- row GEMM: one k-row or v-row x 32 cols ----
        float acc[TN];
#pragma unroll
        for (int j = 0; j < TN; ++j) acc[j] = 0.f;
#pragma unroll 4
        for (int c = 0; c < CC; ++c) {
            float w = wT[c * 768 + wcol];
            const float4* xrow = (const float4*)&xs[c][0];
#pragma unroll
            for (int j4 = 0; j4 < TN / 4; ++j4) {
                float4 xv = xrow[j4];
                acc[j4 * 4 + 0] += w * xv.x;
                acc[j4 * 4 + 1] += w * xv.y;
                acc[j4 * 4 + 2] += w * xv.z;
                acc[j4 * 4 + 3] += w * xv.w;
            }
        }
        // ---- exp (k rows) and publish rows to LDS ----
        if (half == 0) {
            float s = 0.f;
#pragma unroll
            for (int j = 0; j < TN; ++j) {
                float p = expf(acc[j]);
                acc[j] = p;
                s += p;
            }
            zacc += s;
#pragma unroll
            for (int j = 0; j < TN; ++j) ps[r][j] = acc[j];
        } else {
#pragma unroll
            for (int j = 0; j < TN; ++j) vs[r][j] = acc[j];
        }
        __syncthreads();
        // ---- context update: C[e] += sum_j p[r][j] * v[h*32 + half*16 + e][j] ----
        float prow[TN];
        {
            const float4* pr = (const float4*)&ps[r][0];
#pragma unroll
            for (int j4 = 0; j4 < TN / 4; ++j4) {
                float4 pv = pr[j4];
                prow[j4 * 4 + 0] = pv.x;
                prow[j4 * 4 + 1] = pv.y;
                prow[j4 * 4 + 2] = pv.z;
                prow[j4 * 4 + 3] = pv.w;
            }
        }
#pragma unroll
        for (int e = 0; e < 16; ++e) {
            const float4* vrow = (const float4*)&vs[h * 32 + half * 16 + e][0];
            float cacc = C[e];
#pragma unroll
            for (int j4 = 0; j4 < TN / 4; ++j4) {
                float4 vv = vrow[j4];
                cacc += prow[j4 * 4 + 0] * vv.x;
                cacc += prow[j4 * 4 + 1] * vv.y;
                cacc += prow[j4 * 4 + 2] * vv.z;
                cacc += prow[j4 * 4 + 3] * vv.w;
            }
            C[e] = cacc;
        }
        __syncthreads();   // C-update done before next tile overwrites ps/vs/xs
    }

    // ---- write partials ----
    size_t base = ((size_t)(bf * NS + ns) * 256 + r) * 32 + half * 16;
#pragma unroll
    for (int e = 0; e < 16; ++e) partC[base + e] = C[e];
    if (half == 0) partz[(size_t)(bf * NS + ns) * 256 + r] = zacc;
}

// K2: merge partials -> context; fold with w_out -> Mt[bf][hd][o] (SCALE folded in)
__global__ __launch_bounds__(256) void k2_M(const float* __restrict__ partC,
                                            const float* __restrict__ partz,
                                            const float* __restrict__ wout,
                                            float* __restrict__ Mt) {
    const int bf = blockIdx.x;
    const int t = threadIdx.x;
    __shared__ float ctxs[256][33];

    float z = 0.f;
#pragma unroll
    for (int ns2 = 0; ns2 < NS; ++ns2) z += partz[(size_t)(bf * NS + ns2) * 256 + t];
    float inv = 1.f / z;
#pragma unroll
    for (int e = 0; e < 32; ++e) {
        float c = 0.f;
#pragma unroll
        for (int ns2 = 0; ns2 < NS; ++ns2)
            c += partC[((size_t)(bf * NS + ns2) * 256 + t) * 32 + e];
        ctxs[t][e] = c * inv;
    }
    __syncthreads();

    const int o = t;
    for (int h = 0; h < HEADS; ++h) {
        float wo[32];
#pragma unroll
        for (int e = 0; e < 32; ++e) wo[e] = wout[o * 256 + h * 32 + e];
        for (int d = 0; d < 32; ++d) {
            float m = 0.f;
#pragma unroll
            for (int e = 0; e < 32; ++e) m += wo[e] * ctxs[h * 32 + d][e];
            Mt[((size_t)bf * 256 + h * 32 + d) * 256 + o] = m * SCALEF;
        }
    }
}

// K3: per (bf, n-tile): q = Wq @ X; softmax over d per head per column; out = Mt^T-apply + bias
__global__ __launch_bounds__(512) void k3_out(const float* __restrict__ x,
                                              const float* __restrict__ wT,
                                              const float* __restrict__ Mt,
                                              const float* __restrict__ bout,
                                              float* __restrict__ out) {
    const int tile = blockIdx.x;    // 0..127
    const int bf = blockIdx.y;
    const int b = bf >> 4, f = bf & 15;
    const size_t xoff = (size_t)b * (CC * FF * NN) + (size_t)f * NN;
    const float* xbase = x + xoff;
    float* obase = out + xoff;
    const int n0 = tile * TN;
    const int t = threadIdx.x;
    const int r = t & 255;
    const int jh = (t >> 8) * 16;   // column half

    __shared__ float xs[256][36];
    __shared__ float qs[256][36];

    // stage X tile
#pragma unroll
    for (int kk = 0; kk < 16; ++kk) {
        int idx = t + kk * 512;
        int c = idx >> 5, j = idx & 31;
        xs[c][j] = xbase[(size_t)c * (FF * NN) + n0 + j];
    }
    __syncthreads();

    // q GEMM: row r, cols [jh, jh+16)
    {
        float acc[16];
#pragma unroll
        for (int j = 0; j < 16; ++j) acc[j] = 0.f;
#pragma unroll 4
        for (int c = 0; c < CC; ++c) {
            float w = wT[c * 768 + r];
            const float4* xrow = (const float4*)&xs[c][jh];
#pragma unroll
            for (int j4 = 0; j4 < 4; ++j4) {
                float4 xv = xrow[j4];
                acc[j4 * 4 + 0] += w * xv.x;
                acc[j4 * 4 + 1] += w * xv.y;
                acc[j4 * 4 + 2] += w * xv.z;
                acc[j4 * 4 + 3] += w * xv.w;
            }
        }
        float4* qrow = (float4*)&qs[r][jh];
#pragma unroll
        for (int j4 = 0; j4 < 4; ++j4) {
            float4 v;
            v.x = acc[j4 * 4 + 0];
            v.y = acc[j4 * 4 + 1];
            v.z = acc[j4 * 4 + 2];
            v.w = acc[j4 * 4 + 3];
            qrow[j4] = v;
        }
    }
    __syncthreads();

    // softmax over d (32) per (head, column)
    if (t < 256) {
        const int h = t >> 5, j = t & 31;
        float e[32];
        float s = 0.f;
#pragma unroll
        for (int d = 0; d < 32; ++d) {
            e[d] = expf(qs[h * 32 + d][j]);
            s += e[d];
        }
        float inv = 1.f / s;
#pragma unroll
        for (int d = 0; d < 32; ++d) qs[h * 32 + d][j] = e[d] * inv;
    }
    __syncthreads();

    // out GEMM: out[o][jh..jh+15] = b[o] + sum_hd Mt[bf][hd][o] * qs[hd][j]
    {
        const int o = r;
        float acc[16];
#pragma unroll
        for (int j = 0; j < 16; ++j) acc[j] = 0.f;
        const float* mptr = Mt + (size_t)bf * 65536 + o;
#pragma unroll 4
        for (int hd = 0; hd < 256; ++hd) {
            float m = mptr[(size_t)hd * 256];
            const float4* qrow = (const float4*)&qs[hd][jh];
#pragma unroll
            for (int j4 = 0; j4 < 4; ++j4) {
                float4 qv = qrow[j4];
                acc[j4 * 4 + 0] += m * qv.x;
                acc[j4 * 4 + 1] += m * qv.y;
                acc[j4 * 4 + 2] += m * qv.z;
                acc[j4 * 4 + 3] += m * qv.w;
            }
        }
        float bb = bout[o];
        // xs is free (last read was q-GEMM, two barriers ago): stage output for coalesced store
#pragma unroll
        for (int j = 0; j < 16; ++j) xs[o][jh + j] = acc[j] + bb;
    }
    __syncthreads();

    // coalesced store
#pragma unroll
    for (int kk = 0; kk < 16; ++kk) {
        int idx = t + kk * 512;
        int o = idx >> 5, j = idx & 31;
        obase[(size_t)o * (FF * NN) + n0 + j] = xs[o][j];
    }
}

extern "C" void kernel_launch(void* const* d_in, const int* in_sizes, int n_in,
                              void* d_out, int out_size, void* d_ws, size_t ws_size,
                              hipStream_t stream) {
    const float* x    = (const float*)d_in[0];
    const float* wqkv = (const float*)d_in[1];
    const float* wout = (const float*)d_in[2];
    const float* bout = (const float*)d_in[3];
    float* out = (float*)d_out;
    float* ws  = (float*)d_ws;

    float* wT    = ws + WT_OFF;
    float* partC = ws + PARTC_OFF;
    float* partz = ws + PARTZ_OFF;
    float* Mt    = ws + MT_OFF;

    k0_transpose<<<768, 256, 0, stream>>>(wqkv, wT);
    k1_context<<<dim3(NS, BF), 512, 0, stream>>>(x, wT, partC, partz);
    k2_M<<<BF, 256, 0, stream>>>(partC, partz, wout, Mt);
    k3_out<<<dim3(NN / TN, BF), 512, 0, stream>>>(x, wT, Mt, bout, out);
}

// Round 2
// 961.978 us; speedup vs baseline: 2.2013x; 2.2013x over previous
//
#include <hip/hip_runtime.h>
#include <math.h>

// Problem constants
#define BB    2
#define CC    256
#define FF    16
#define NN    4096      // 64*64 spatial
#define FN    (FF*NN)   // 65536
#define BF    32        // BB*FF
#define HEADS 8
#define DH    32
#define HID   256
#define NS    8         // n-range splits in K1
#define TN    32        // n tile width (K1)
#define TN3   64        // n tile width (K3)
#define SCALEF 0.17677669529663687f   // 32^-0.5

// ws layout (in floats)
#define WT2_OFF   0                          // wT2[256 c][512 kv-rows] fp32
#define PARTC_OFF (256*512)                  // partC[BF][NS][256][32]
#define PARTZ_OFF (PARTC_OFF + BF*NS*256*32) // partz[BF][NS][256]
#define USH_OFF   (PARTZ_OFF + BF*NS*256)    // ushort region below (float idx 2293760)
// ushort offsets within U = (ushort*)(ws + USH_OFF):
#define WQHI_O 0                    // [256 r][256 c]
#define WQLO_O 65536
#define MHI_O  131072               // [BF][256 o][256 hd]
#define MLO_O  (131072 + BF*256*256)
// total = 131072 + 2097152 + 65536 + (4325376/2) = 4456448 floats (17.8 MiB, proven fit)

typedef __attribute__((ext_vector_type(8))) short bf16x8;
typedef __attribute__((ext_vector_type(8))) unsigned short u16x8;
typedef __attribute__((ext_vector_type(4))) unsigned short u16x4;
typedef __attribute__((ext_vector_type(4))) float f32x4;

#define MFMA16(a, b, c) __builtin_amdgcn_mfma_f32_16x16x32_bf16((a), (b), (c), 0, 0, 0)

__device__ inline unsigned short f2bf(float f) {
    unsigned int u = __float_as_uint(f);
    unsigned int r = (u + 0x7fffu + ((u >> 16) & 1u)) >> 16;
    return (unsigned short)r;
}
__device__ inline float bf2f(unsigned short h) {
    return __uint_as_float(((unsigned int)h) << 16);
}

// K0: wT2[c][512] = w_qkv rows 256..767 transposed (for fp32 K1);
//     Wq hi/lo bf16 row-major (rows 0..255) for K3's MFMA A-operand.
__global__ __launch_bounds__(256) void k0_prep(const float* __restrict__ wqkv,
                                               float* __restrict__ wT2,
                                               unsigned short* __restrict__ wqhi,
                                               unsigned short* __restrict__ wqlo) {
    int idx = blockIdx.x * 256 + threadIdx.x;   // 0 .. 768*256
    int o = idx >> 8;
    int c = idx & 255;
    float v = wqkv[idx];
    if (o < 256) {
        unsigned short hv = f2bf(v);
        wqhi[o * 256 + c] = hv;
        wqlo[o * 256 + c] = f2bf(v - bf2f(hv));
    } else {
        wT2[c * 512 + (o - 256)] = v;
    }
}

// K1: per (bf, n-split): k,v = W_{k,v} @ X on n-tiles; accumulate
// partC[hd][e] = sum_n exp(k[hd,n]) * v[(h,e),n], partz[hd] = sum_n exp(k[hd,n])
__global__ __launch_bounds__(512) void k1_context(const float* __restrict__ x,
                                                  const float* __restrict__ wT2,
                                                  float* __restrict__ partC,
                                                  float* __restrict__ partz) {
    const int ns = blockIdx.x;
    const int bf = blockIdx.y;
    const int b = bf >> 4, f = bf & 15;
    const float* xbase = x + (size_t)b * (CC * FN) + (size_t)f * NN;
    const int t = threadIdx.x;
    const int r = t & 255;
    const int half = t >> 8;        // 0: k rows, 1: v rows
    const int h = r >> 5;

    __shared__ float xs[256][36];
    __shared__ float vs[256][36];
    __shared__ float ps[256][36];

    float C[16];
#pragma unroll
    for (int e = 0; e < 16; ++e) C[e] = 0.f;
    float zacc = 0.f;

    const int wcol = half * 256 + r;   // index into wT2's 512 kv-rows

    for (int tile = 0; tile < (NN / NS) / TN; ++tile) {
        const int n0 = ns * (NN / NS) + tile * TN;
#pragma unroll
        for (int kk = 0; kk < 16; ++kk) {
            int idx = t + kk * 512;
            int c = idx >> 5, j = idx & 31;
            xs[c][j] = xbase[(size_t)c * FN + n0 + j];
        }
        __syncthreads();
        float acc[TN];
#pragma unroll
        for (int j = 0; j < TN; ++j) acc[j] = 0.f;
#pragma unroll 4
        for (int c = 0; c < CC; ++c) {
            float w = wT2[c * 512 + wcol];
            const float4* xrow = (const float4*)&xs[c][0];
#pragma unroll
            for (int j4 = 0; j4 < TN / 4; ++j4) {
                float4 xv = xrow[j4];
                acc[j4 * 4 + 0] += w * xv.x;
                acc[j4 * 4 + 1] += w * xv.y;
                acc[j4 * 4 + 2] += w * xv.z;
                acc[j4 * 4 + 3] += w * xv.w;
            }
        }
        if (half == 0) {
            float s = 0.f;
#pragma unroll
            for (int j = 0; j < TN; ++j) {
                float p = expf(acc[j]);
                acc[j] = p;
                s += p;
            }
            zacc += s;
#pragma unroll
            for (int j = 0; j < TN; ++j) ps[r][j] = acc[j];
        } else {
#pragma unroll
            for (int j = 0; j < TN; ++j) vs[r][j] = acc[j];
        }
        __syncthreads();
        float prow[TN];
        {
            const float4* pr = (const float4*)&ps[r][0];
#pragma unroll
            for (int j4 = 0; j4 < TN / 4; ++j4) {
                float4 pv = pr[j4];
                prow[j4 * 4 + 0] = pv.x;
                prow[j4 * 4 + 1] = pv.y;
                prow[j4 * 4 + 2] = pv.z;
                prow[j4 * 4 + 3] = pv.w;
            }
        }
#pragma unroll
        for (int e = 0; e < 16; ++e) {
            const float4* vrow = (const float4*)&vs[h * 32 + half * 16 + e][0];
            float cacc = C[e];
#pragma unroll
            for (int j4 = 0; j4 < TN / 4; ++j4) {
                float4 vv = vrow[j4];
                cacc += prow[j4 * 4 + 0] * vv.x;
                cacc += prow[j4 * 4 + 1] * vv.y;
                cacc += prow[j4 * 4 + 2] * vv.z;
                cacc += prow[j4 * 4 + 3] * vv.w;
            }
            C[e] = cacc;
        }
        __syncthreads();
    }

    size_t base = ((size_t)(bf * NS + ns) * 256 + r) * 32 + half * 16;
#pragma unroll
    for (int e = 0; e < 16; ++e) partC[base + e] = C[e];
    if (half == 0) partz[(size_t)(bf * NS + ns) * 256 + r] = zacc;
}

// K2: merge partials -> ctx (SCALE folded); M[o][hd] = sum_e wout[o][32h+e]*ctx[hd][e]
// emitted as bf16 hi/lo row-major [bf][o][hd] (A-operand for K3 GEMM2).
__global__ __launch_bounds__(256) void k2_M(const float* __restrict__ partC,
                                            const float* __restrict__ partz,
                                            const float* __restrict__ wout,
                                            unsigned short* __restrict__ Mhi,
                                            unsigned short* __restrict__ Mlo) {
    const int bf = blockIdx.x;
    const int t = threadIdx.x;   // = hd
    const int h = t >> 5;

    float z = 0.f;
#pragma unroll
    for (int ns2 = 0; ns2 < NS; ++ns2) z += partz[(size_t)(bf * NS + ns2) * 256 + t];
    float inv = SCALEF / z;
    float ctx[32];
#pragma unroll
    for (int e = 0; e < 32; ++e) {
        float c = 0.f;
#pragma unroll
        for (int ns2 = 0; ns2 < NS; ++ns2)
            c += partC[((size_t)(bf * NS + ns2) * 256 + t) * 32 + e];
        ctx[e] = c * inv;
    }

    __shared__ float wos[8][256];
    for (int ob = 0; ob < 256; ob += 8) {
        __syncthreads();
#pragma unroll
        for (int i = 0; i < 8; ++i) wos[i][t] = wout[(ob + i) * 256 + t];
        __syncthreads();
#pragma unroll
        for (int oo = 0; oo < 8; ++oo) {
            float mv = 0.f;
#pragma unroll
            for (int e = 0; e < 32; ++e) mv += wos[oo][32 * h + e] * ctx[e];
            unsigned short hv = f2bf(mv);
            unsigned short lv = f2bf(mv - bf2f(hv));
            size_t idx = (size_t)bf * 65536 + (size_t)(ob + oo) * 256 + t;
            Mhi[idx] = hv;
            Mlo[idx] = lv;
        }
    }
}

// K3 (MFMA): per (bf, 64-col tile):
//   Q = Wq @ X  (split-bf16, 3 MFMA)  -> in-register softmax over d per column
//   OUT = M @ Qsm (split-bf16)        -> + bias -> store
__global__ __launch_bounds__(512, 4) void k3_mfma(const float* __restrict__ x,
                                                  const unsigned short* __restrict__ wqhi,
                                                  const unsigned short* __restrict__ wqlo,
                                                  const unsigned short* __restrict__ mhi,
                                                  const unsigned short* __restrict__ mlo,
                                                  const float* __restrict__ bout,
                                                  float* __restrict__ out) {
    const int tile = blockIdx.x;    // 0..63
    const int bf = blockIdx.y;
    const int b = bf >> 4, f = bf & 15;
    const size_t xoff = (size_t)b * (CC * FN) + (size_t)f * NN;
    const float* xg = x + xoff;
    float* og = out + xoff;
    const int n0 = tile * TN3;
    const int t = threadIdx.x;
    const int w = t >> 6;           // wave 0..7 (= head for GEMM1)
    const int l = t & 63;
    const int g = l >> 4, m = l & 15;

    // planes: [0]=hi, [1]=lo. Phase A: XT[n][256 c]. Phase B (aliased): QsmT[n][256 hd].
    __shared__ unsigned short lds[2][64][256];
    char* L0 = (char*)&lds[0][0][0];
    char* L1 = (char*)&lds[1][0][0];

    // ---- stage: transpose X[c][n] -> XT[n][c] bf16 hi/lo, swizzled ----
    // wave w owns c in [32w, 32w+32); lane owns column n = l.
#pragma unroll
    for (int q = 0; q < 4; ++q) {
        int c0 = 32 * w + 8 * q;
        float v[8];
#pragma unroll
        for (int i = 0; i < 8; ++i) v[i] = xg[(size_t)(c0 + i) * FN + n0 + l];
        u16x8 vh, vl;
#pragma unroll
        for (int i = 0; i < 8; ++i) {
            unsigned short hv = f2bf(v[i]);
            vh[i] = hv;
            vl[i] = f2bf(v[i] - bf2f(hv));
        }
        int off = (l * 512 + c0 * 2) ^ ((l & 7) << 4);
        *(u16x8*)(L0 + off) = vh;
        *(u16x8*)(L1 + off) = vl;
    }
    __syncthreads();

    // ---- GEMM1: qacc[rf][cg] = Q[32w+16rf+4g+r][n0+16cg+m], split-bf16 ----
    f32x4 qacc[2][4];
#pragma unroll
    for (int rf = 0; rf < 2; ++rf)
#pragma unroll
        for (int cg = 0; cg < 4; ++cg) qacc[rf][cg] = (f32x4)0.f;

    for (int kc = 0; kc < 8; ++kc) {
        bf16x8 ah[2], al[2];
#pragma unroll
        for (int rf = 0; rf < 2; ++rf) {
            int r = 32 * w + 16 * rf + m;
            ah[rf] = *(const bf16x8*)(wqhi + r * 256 + 32 * kc + 8 * g);
            al[rf] = *(const bf16x8*)(wqlo + r * 256 + 32 * kc + 8 * g);
        }
        bf16x8 bh[4], bl[4];
#pragma unroll
        for (int cg = 0; cg < 4; ++cg) {
            int n = 16 * cg + m;
            int off = (n * 512 + (32 * kc + 8 * g) * 2) ^ ((n & 7) << 4);
            bh[cg] = *(const bf16x8*)(L0 + off);
            bl[cg] = *(const bf16x8*)(L1 + off);
        }
#pragma unroll
        for (int rf = 0; rf < 2; ++rf)
#pragma unroll
            for (int cg = 0; cg < 4; ++cg) {
                qacc[rf][cg] = MFMA16(ah[rf], bh[cg], qacc[rf][cg]);
                qacc[rf][cg] = MFMA16(ah[rf], bl[cg], qacc[rf][cg]);
                qacc[rf][cg] = MFMA16(al[rf], bh[cg], qacc[rf][cg]);
            }
    }

    // ---- softmax over d (in-register; head = w). exp in place, z via shfl over g ----
    float zinv[4];
#pragma unroll
    for (int cg = 0; cg < 4; ++cg) {
        float s = 0.f;
#pragma unroll
        for (int rf = 0; rf < 2; ++rf)
#pragma unroll
            for (int r = 0; r < 4; ++r) {
                float e = expf(qacc[rf][cg][r]);
                qacc[rf][cg][r] = e;
                s += e;
            }
        s += __shfl_xor(s, 16);
        s += __shfl_xor(s, 32);
        zinv[cg] = 1.f / s;   // SCALE folded into M
    }

    __syncthreads();   // all waves done reading XT before aliasing

    // ---- write QsmT[n][hd] bf16 hi/lo (aliased over XT planes) ----
#pragma unroll
    for (int rf = 0; rf < 2; ++rf)
#pragma unroll
        for (int cg = 0; cg < 4; ++cg) {
            int n = 16 * cg + m;
            int hd0 = 32 * w + 16 * rf + 4 * g;
            u16x4 vh, vl;
#pragma unroll
            for (int r = 0; r < 4; ++r) {
                float qv = qacc[rf][cg][r] * zinv[cg];
                unsigned short hv = f2bf(qv);
                vh[r] = hv;
                vl[r] = f2bf(qv - bf2f(hv));
            }
            int off = (n * 512 + hd0 * 2) ^ ((n & 7) << 4);
            *(u16x4*)(L0 + off) = vh;
            *(u16x4*)(L1 + off) = vl;
        }
    __syncthreads();

    // ---- GEMM2: oacc[rf][cg] = OUT[32w+16rf+4g+r][n0+16cg+m], split-bf16 ----
    f32x4 oacc[2][4];
#pragma unroll
    for (int rf = 0; rf < 2; ++rf)
#pragma unroll
        for (int cg = 0; cg < 4; ++cg) oacc[rf][cg] = (f32x4)0.f;

    const unsigned short* Mh = mhi + (size_t)bf * 65536;
    const unsigned short* Ml = mlo + (size_t)bf * 65536;
    for (int kc = 0; kc < 8; ++kc) {
        bf16x8 ah[2], al[2];
#pragma unroll
        for (int rf = 0; rf < 2; ++rf) {
            int r = 32 * w + 16 * rf + m;
            ah[rf] = *(const bf16x8*)(Mh + r * 256 + 32 * kc + 8 * g);
            al[rf] = *(const bf16x8*)(Ml + r * 256 + 32 * kc + 8 * g);
        }
        bf16x8 bh[4], bl[4];
#pragma unroll
        for (int cg = 0; cg < 4; ++cg) {
            int n = 16 * cg + m;
            int off = (n * 512 + (32 * kc + 8 * g) * 2) ^ ((n & 7) << 4);
            bh[cg] = *(const bf16x8*)(L0 + off);
            bl[cg] = *(const bf16x8*)(L1 + off);
        }
#pragma unroll
        for (int rf = 0; rf < 2; ++rf)
#pragma unroll
            for (int cg = 0; cg < 4; ++cg) {
                oacc[rf][cg] = MFMA16(ah[rf], bh[cg], oacc[rf][cg]);
                oacc[rf][cg] = MFMA16(ah[rf], bl[cg], oacc[rf][cg]);
                oacc[rf][cg] = MFMA16(al[rf], bh[cg], oacc[rf][cg]);
            }
    }

    // ---- epilogue: + bias, direct stores ----
#pragma unroll
    for (int rf = 0; rf < 2; ++rf) {
        float bb[4];
#pragma unroll
        for (int r = 0; r < 4; ++r) bb[r] = bout[32 * w + 16 * rf + 4 * g + r];
#pragma unroll
        for (int cg = 0; cg < 4; ++cg) {
            int n = n0 + 16 * cg + m;
#pragma unroll
            for (int r = 0; r < 4; ++r) {
                int o = 32 * w + 16 * rf + 4 * g + r;
                og[(size_t)o * FN + n] = oacc[rf][cg][r] + bb[r];
            }
        }
    }
}

extern "C" void kernel_launch(void* const* d_in, const int* in_sizes, int n_in,
                              void* d_out, int out_size, void* d_ws, size_t ws_size,
                              hipStream_t stream) {
    const float* x    = (const float*)d_in[0];
    const float* wqkv = (const float*)d_in[1];
    const float* wout = (const float*)d_in[2];
    const float* bout = (const float*)d_in[3];
    float* out = (float*)d_out;
    float* ws  = (float*)d_ws;

    float* wT2   = ws + WT2_OFF;
    float* partC = ws + PARTC_OFF;
    float* partz = ws + PARTZ_OFF;
    unsigned short* U = (unsigned short*)(ws + USH_OFF);
    unsigned short* wqhi = U + WQHI_O;
    unsigned short* wqlo = U + WQLO_O;
    unsigned short* Mhi  = U + MHI_O;
    unsigned short* Mlo  = U + MLO_O;

    k0_prep<<<768, 256, 0, stream>>>(wqkv, wT2, wqhi, wqlo);
    k1_context<<<dim3(NS, BF), 512, 0, stream>>>(x, wT2, partC, partz);
    k2_M<<<BF, 256, 0, stream>>>(partC, partz, wout, Mhi, Mlo);
    k3_mfma<<<dim3(NN / TN3, BF), 512, 0, stream>>>(x, wqhi, wqlo, Mhi, Mlo, bout, out);
}

// Round 3
// 501.060 us; speedup vs baseline: 4.2263x; 1.9199x over previous
//
#include <hip/hip_runtime.h>
#include <math.h>

// Problem constants
#define BB    2
#define CC    256
#define FF    16
#define NN    4096      // 64*64 spatial
#define FN    (FF*NN)   // 65536
#define BF    32        // BB*FF
#define HEADS 8
#define DH    32
#define HID   256
#define NS    8         // n-range splits in K1
#define TN1   32        // n tile width (K1)
#define TN3   64        // n tile width (K3)
#define SCALEF 0.17677669529663687f   // 32^-0.5

// ws layout (in floats)
#define PARTC_OFF 0                          // partC[BF][NS][256][32]
#define PARTZ_OFF (BF*NS*256*32)             // partz[BF][NS][256]
#define USH_OFF   (PARTZ_OFF + BF*NS*256)    // ushort region below
// ushort offsets within U = (ushort*)(ws + USH_OFF):
#define WQHI_O  0                    // [256 r][256 c]
#define WQLO_O  65536
#define WKVHI_O 131072               // [512 kv][256 c]
#define WKVLO_O 262144
#define MHI_O   393216               // [BF][256 o][256 hd]
#define MLO_O   (393216 + BF*256*256)
// floats: 2097152 + 65536 + 4587520/2 = 4456448 floats (~17.8 MiB, proven fit)

typedef __attribute__((ext_vector_type(8))) short bf16x8;
typedef __attribute__((ext_vector_type(8))) unsigned short u16x8;
typedef __attribute__((ext_vector_type(4))) unsigned short u16x4;
typedef __attribute__((ext_vector_type(4))) float f32x4;

#define MFMA16(a, b, c) __builtin_amdgcn_mfma_f32_16x16x32_bf16((a), (b), (c), 0, 0, 0)

__device__ inline unsigned short f2bf(float f) {
    unsigned int u = __float_as_uint(f);
    unsigned int r = (u + 0x7fffu + ((u >> 16) & 1u)) >> 16;
    return (unsigned short)r;
}
__device__ inline float bf2f(unsigned short h) {
    return __uint_as_float(((unsigned int)h) << 16);
}

// K0: split all of w_qkv into bf16 hi/lo row-major: Wq rows 0..255, Wkv rows 256..767.
__global__ __launch_bounds__(256) void k0_prep(const float* __restrict__ wqkv,
                                               unsigned short* __restrict__ wqhi,
                                               unsigned short* __restrict__ wqlo,
                                               unsigned short* __restrict__ wkvhi,
                                               unsigned short* __restrict__ wkvlo) {
    int idx = blockIdx.x * 256 + threadIdx.x;   // 0 .. 768*256
    int o = idx >> 8;
    int c = idx & 255;
    float v = wqkv[idx];
    unsigned short hv = f2bf(v);
    unsigned short lv = f2bf(v - bf2f(hv));
    if (o < 256) {
        wqhi[o * 256 + c] = hv;
        wqlo[o * 256 + c] = lv;
    } else {
        int r = o - 256;
        wkvhi[r * 256 + c] = hv;
        wkvlo[r * 256 + c] = lv;
    }
}

// K1 (MFMA): per (bf, ns): for each 32-col tile:
//   D[n][kv] = XT·Wkv^T (split-bf16); exp on k-cols; z via shfl;
//   P/V bf16 hi/lo -> LDS; per-head context MFMA C_h += P_h·V_h^T (K=n).
__global__ __launch_bounds__(512) void k1_mfma(const float* __restrict__ x,
                                               const unsigned short* __restrict__ wkvhi,
                                               const unsigned short* __restrict__ wkvlo,
                                               float* __restrict__ partC,
                                               float* __restrict__ partz) {
    const int ns = blockIdx.x;
    const int bf = blockIdx.y;
    const int b = bf >> 4, f = bf & 15;
    const float* xbase = x + (size_t)b * (CC * FN) + (size_t)f * NN;
    const int t = threadIdx.x;
    const int w = t >> 6;           // wave 0..7
    const int l = t & 63;
    const int g = l >> 4, m = l & 15;
    const int h = w;                // head for context phase

    __shared__ uint4 LDSv[4096];    // 64 KiB
    char* X0 = (char*)LDSv;         // XT hi [32 n][256 c] bf16, swizzled
    char* X1 = X0 + 16384;          // XT lo
    char* P0 = X0;                  // P hi [256 hd][32 n] (aliases XT after barrier)
    char* P1 = X0 + 16384;          // P lo
    char* V0 = X0 + 32768;          // V hi [256 he][32 n]
    char* V1 = X0 + 49152;          // V lo

    f32x4 ctx[2][2];
#pragma unroll
    for (int df = 0; df < 2; ++df)
#pragma unroll
        for (int ef = 0; ef < 2; ++ef) ctx[df][ef] = (f32x4)0.f;
    float zacc[4] = {0.f, 0.f, 0.f, 0.f};

    const unsigned short* bbh = wkvhi + (64 * w + m) * 256 + 8 * g;
    const unsigned short* bbl = wkvlo + (64 * w + m) * 256 + 8 * g;

    for (int tile = 0; tile < 16; ++tile) {
        const int n0 = ns * 512 + tile * TN1;

        // ---- stage XT[n][c] bf16 hi/lo (swizzled) ----
        {
            const int nl = t & 31;
            const int c0 = (t >> 5) << 4;   // 16 c's per thread
            float v[16];
#pragma unroll
            for (int i = 0; i < 16; ++i) v[i] = xbase[(size_t)(c0 + i) * FN + n0 + nl];
#pragma unroll
            for (int qq = 0; qq < 2; ++qq) {
                u16x8 vh, vl;
#pragma unroll
                for (int i = 0; i < 8; ++i) {
                    float fv = v[qq * 8 + i];
                    unsigned short hv = f2bf(fv);
                    vh[i] = hv;
                    vl[i] = f2bf(fv - bf2f(hv));
                }
                int off = (nl * 512 + (c0 + qq * 8) * 2) ^ ((nl & 7) << 4);
                *(u16x8*)(X0 + off) = vh;
                *(u16x8*)(X1 + off) = vl;
            }
        }
        __syncthreads();

        // ---- GEMM1: acc[rf][cg] = D[n=16rf+4g+r][kv=64w+16cg+m], split-bf16 ----
        f32x4 acc[2][4];
#pragma unroll
        for (int rf = 0; rf < 2; ++rf)
#pragma unroll
            for (int cg = 0; cg < 4; ++cg) acc[rf][cg] = (f32x4)0.f;

#pragma unroll 2
        for (int kc = 0; kc < 8; ++kc) {
            bf16x8 ah[2], al[2];
#pragma unroll
            for (int rf = 0; rf < 2; ++rf) {
                int n = 16 * rf + m;
                int off = (n * 512 + (32 * kc + 8 * g) * 2) ^ ((n & 7) << 4);
                ah[rf] = *(const bf16x8*)(X0 + off);
                al[rf] = *(const bf16x8*)(X1 + off);
            }
            bf16x8 bh[4], bl[4];
#pragma unroll
            for (int cg = 0; cg < 4; ++cg) {
                bh[cg] = *(const bf16x8*)(bbh + cg * 16 * 256 + kc * 32);
                bl[cg] = *(const bf16x8*)(bbl + cg * 16 * 256 + kc * 32);
            }
#pragma unroll
            for (int rf = 0; rf < 2; ++rf)
#pragma unroll
                for (int cg = 0; cg < 4; ++cg) {
                    acc[rf][cg] = MFMA16(ah[rf], bh[cg], acc[rf][cg]);
                    acc[rf][cg] = MFMA16(ah[rf], bl[cg], acc[rf][cg]);
                    acc[rf][cg] = MFMA16(al[rf], bh[cg], acc[rf][cg]);
                }
        }
        __syncthreads();   // XT dead; PV region may be overwritten

        // ---- exp + z (k-waves), write P/V bf16 hi/lo ----
        if (w < 4) {
#pragma unroll
            for (int rf = 0; rf < 2; ++rf)
#pragma unroll
                for (int cg = 0; cg < 4; ++cg)
#pragma unroll
                    for (int r = 0; r < 4; ++r) acc[rf][cg][r] = expf(acc[rf][cg][r]);
#pragma unroll
            for (int cg = 0; cg < 4; ++cg) {
                float s = 0.f;
#pragma unroll
                for (int rf = 0; rf < 2; ++rf)
#pragma unroll
                    for (int r = 0; r < 4; ++r) s += acc[rf][cg][r];
                s += __shfl_xor(s, 16);
                s += __shfl_xor(s, 32);
                zacc[cg] += s;
            }
#pragma unroll
            for (int rf = 0; rf < 2; ++rf)
#pragma unroll
                for (int cg = 0; cg < 4; ++cg) {
                    int row = 64 * w + 16 * cg + m;
                    u16x4 vh, vl;
#pragma unroll
                    for (int r = 0; r < 4; ++r) {
                        float fv = acc[rf][cg][r];
                        unsigned short hv = f2bf(fv);
                        vh[r] = hv;
                        vl[r] = f2bf(fv - bf2f(hv));
                    }
                    int off = (row * 64 + (16 * rf + 4 * g) * 2) ^ ((row & 3) << 4);
                    *(u16x4*)(P0 + off) = vh;
                    *(u16x4*)(P1 + off) = vl;
                }
        } else {
#pragma unroll
            for (int rf = 0; rf < 2; ++rf)
#pragma unroll
                for (int cg = 0; cg < 4; ++cg) {
                    int row = 64 * (w - 4) + 16 * cg + m;
                    u16x4 vh, vl;
#pragma unroll
                    for (int r = 0; r < 4; ++r) {
                        float fv = acc[rf][cg][r];
                        unsigned short hv = f2bf(fv);
                        vh[r] = hv;
                        vl[r] = f2bf(fv - bf2f(hv));
                    }
                    int off = (row * 64 + (16 * rf + 4 * g) * 2) ^ ((row & 3) << 4);
                    *(u16x4*)(V0 + off) = vh;
                    *(u16x4*)(V1 + off) = vl;
                }
        }
        __syncthreads();

        // ---- context MFMA: ctx[df][ef] += P_h[d][n]·V_h[e][n], K=32 ----
        {
            bf16x8 ph[2], pl[2], vh_[2], vl_[2];
#pragma unroll
            for (int df = 0; df < 2; ++df) {
                int row = 32 * h + 16 * df + m;
                int off = (row * 64 + 16 * g) ^ ((row & 3) << 4);
                ph[df] = *(const bf16x8*)(P0 + off);
                pl[df] = *(const bf16x8*)(P1 + off);
            }
#pragma unroll
            for (int ef = 0; ef < 2; ++ef) {
                int row = 32 * h + 16 * ef + m;
                int off = (row * 64 + 16 * g) ^ ((row & 3) << 4);
                vh_[ef] = *(const bf16x8*)(V0 + off);
                vl_[ef] = *(const bf16x8*)(V1 + off);
            }
#pragma unroll
            for (int df = 0; df < 2; ++df)
#pragma unroll
                for (int ef = 0; ef < 2; ++ef) {
                    ctx[df][ef] = MFMA16(ph[df], vh_[ef], ctx[df][ef]);
                    ctx[df][ef] = MFMA16(ph[df], vl_[ef], ctx[df][ef]);
                    ctx[df][ef] = MFMA16(pl[df], vh_[ef], ctx[df][ef]);
                }
        }
        __syncthreads();   // PV dead before next tile's staging overwrites
    }

    // ---- write partials ----
    if (w < 4 && g == 0) {
#pragma unroll
        for (int cg = 0; cg < 4; ++cg)
            partz[(size_t)(bf * NS + ns) * 256 + 64 * w + 16 * cg + m] = zacc[cg];
    }
#pragma unroll
    for (int df = 0; df < 2; ++df)
#pragma unroll
        for (int ef = 0; ef < 2; ++ef)
#pragma unroll
            for (int r = 0; r < 4; ++r) {
                int row = 32 * h + 16 * df + 4 * g + r;
                int col = 16 * ef + m;
                partC[((size_t)(bf * NS + ns) * 256 + row) * 32 + col] = ctx[df][ef][r];
            }
}

// K2: merge partials -> ctx (SCALE folded); M[o][hd] = sum_e wout[o][32h+e]*ctx[hd][e]
// emitted as bf16 hi/lo row-major [bf][o][hd] (A-operand for K3 GEMM2).
__global__ __launch_bounds__(256) void k2_M(const float* __restrict__ partC,
                                            const float* __restrict__ partz,
                                            const float* __restrict__ wout,
                                            unsigned short* __restrict__ Mhi,
                                            unsigned short* __restrict__ Mlo) {
    const int bf = blockIdx.x;
    const int t = threadIdx.x;   // = hd
    const int h = t >> 5;

    float z = 0.f;
#pragma unroll
    for (int ns2 = 0; ns2 < NS; ++ns2) z += partz[(size_t)(bf * NS + ns2) * 256 + t];
    float inv = SCALEF / z;
    float ctx[32];
#pragma unroll
    for (int e = 0; e < 32; ++e) {
        float c = 0.f;
#pragma unroll
        for (int ns2 = 0; ns2 < NS; ++ns2)
            c += partC[((size_t)(bf * NS + ns2) * 256 + t) * 32 + e];
        ctx[e] = c * inv;
    }

    __shared__ float wos[8][256];
    for (int ob = 0; ob < 256; ob += 8) {
        __syncthreads();
#pragma unroll
        for (int i = 0; i < 8; ++i) wos[i][t] = wout[(ob + i) * 256 + t];
        __syncthreads();
#pragma unroll
        for (int oo = 0; oo < 8; ++oo) {
            float mv = 0.f;
#pragma unroll
            for (int e = 0; e < 32; ++e) mv += wos[oo][32 * h + e] * ctx[e];
            unsigned short hv = f2bf(mv);
            unsigned short lv = f2bf(mv - bf2f(hv));
            size_t idx = (size_t)bf * 65536 + (size_t)(ob + oo) * 256 + t;
            Mhi[idx] = hv;
            Mlo[idx] = lv;
        }
    }
}

// K3 (MFMA): per (bf, 64-col tile):
//   Q = Wq @ X  (split-bf16, 3 MFMA)  -> in-register softmax over d per column
//   OUT = M @ Qsm (split-bf16)        -> + bias -> store
__global__ __launch_bounds__(512, 4) void k3_mfma(const float* __restrict__ x,
                                                  const unsigned short* __restrict__ wqhi,
                                                  const unsigned short* __restrict__ wqlo,
                                                  const unsigned short* __restrict__ mhi,
                                                  const unsigned short* __restrict__ mlo,
                                                  const float* __restrict__ bout,
                                                  float* __restrict__ out) {
    const int tile = blockIdx.x;    // 0..63
    const int bf = blockIdx.y;
    const int b = bf >> 4, f = bf & 15;
    const size_t xoff = (size_t)b * (CC * FN) + (size_t)f * NN;
    const float* xg = x + xoff;
    float* og = out + xoff;
    const int n0 = tile * TN3;
    const int t = threadIdx.x;
    const int w = t >> 6;           // wave 0..7 (= head for GEMM1)
    const int l = t & 63;
    const int g = l >> 4, m = l & 15;

    __shared__ unsigned short lds[2][64][256];
    char* L0 = (char*)&lds[0][0][0];
    char* L1 = (char*)&lds[1][0][0];

    // ---- stage: transpose X[c][n] -> XT[n][c] bf16 hi/lo, swizzled ----
#pragma unroll
    for (int q = 0; q < 4; ++q) {
        int c0 = 32 * w + 8 * q;
        float v[8];
#pragma unroll
        for (int i = 0; i < 8; ++i) v[i] = xg[(size_t)(c0 + i) * FN + n0 + l];
        u16x8 vh, vl;
#pragma unroll
        for (int i = 0; i < 8; ++i) {
            unsigned short hv = f2bf(v[i]);
            vh[i] = hv;
            vl[i] = f2bf(v[i] - bf2f(hv));
        }
        int off = (l * 512 + c0 * 2) ^ ((l & 7) << 4);
        *(u16x8*)(L0 + off) = vh;
        *(u16x8*)(L1 + off) = vl;
    }
    __syncthreads();

    // ---- GEMM1: qacc[rf][cg] = Q[32w+16rf+4g+r][n0+16cg+m], split-bf16 ----
    f32x4 qacc[2][4];
#pragma unroll
    for (int rf = 0; rf < 2; ++rf)
#pragma unroll
        for (int cg = 0; cg < 4; ++cg) qacc[rf][cg] = (f32x4)0.f;

    for (int kc = 0; kc < 8; ++kc) {
        bf16x8 ah[2], al[2];
#pragma unroll
        for (int rf = 0; rf < 2; ++rf) {
            int r = 32 * w + 16 * rf + m;
            ah[rf] = *(const bf16x8*)(wqhi + r * 256 + 32 * kc + 8 * g);
            al[rf] = *(const bf16x8*)(wqlo + r * 256 + 32 * kc + 8 * g);
        }
        bf16x8 bh[4], bl[4];
#pragma unroll
        for (int cg = 0; cg < 4; ++cg) {
            int n = 16 * cg + m;
            int off = (n * 512 + (32 * kc + 8 * g) * 2) ^ ((n & 7) << 4);
            bh[cg] = *(const bf16x8*)(L0 + off);
            bl[cg] = *(const bf16x8*)(L1 + off);
        }
#pragma unroll
        for (int rf = 0; rf < 2; ++rf)
#pragma unroll
            for (int cg = 0; cg < 4; ++cg) {
                qacc[rf][cg] = MFMA16(ah[rf], bh[cg], qacc[rf][cg]);
                qacc[rf][cg] = MFMA16(ah[rf], bl[cg], qacc[rf][cg]);
                qacc[rf][cg] = MFMA16(al[rf], bh[cg], qacc[rf][cg]);
            }
    }

    // ---- softmax over d (in-register; head = w) ----
    float zinv[4];
#pragma unroll
    for (int cg = 0; cg < 4; ++cg) {
        float s = 0.f;
#pragma unroll
        for (int rf = 0; rf < 2; ++rf)
#pragma unroll
            for (int r = 0; r < 4; ++r) {
                float e = expf(qacc[rf][cg][r]);
                qacc[rf][cg][r] = e;
                s += e;
            }
        s += __shfl_xor(s, 16);
        s += __shfl_xor(s, 32);
        zinv[cg] = 1.f / s;   // SCALE folded into M
    }

    __syncthreads();

    // ---- write QsmT[n][hd] bf16 hi/lo (aliased over XT planes) ----
#pragma unroll
    for (int rf = 0; rf < 2; ++rf)
#pragma unroll
        for (int cg = 0; cg < 4; ++cg) {
            int n = 16 * cg + m;
            int hd0 = 32 * w + 16 * rf + 4 * g;
            u16x4 vh, vl;
#pragma unroll
            for (int r = 0; r < 4; ++r) {
                float qv = qacc[rf][cg][r] * zinv[cg];
                unsigned short hv = f2bf(qv);
                vh[r] = hv;
                vl[r] = f2bf(qv - bf2f(hv));
            }
            int off = (n * 512 + hd0 * 2) ^ ((n & 7) << 4);
            *(u16x4*)(L0 + off) = vh;
            *(u16x4*)(L1 + off) = vl;
        }
    __syncthreads();

    // ---- GEMM2: oacc[rf][cg] = OUT[32w+16rf+4g+r][n0+16cg+m], split-bf16 ----
    f32x4 oacc[2][4];
#pragma unroll
    for (int rf = 0; rf < 2; ++rf)
#pragma unroll
        for (int cg = 0; cg < 4; ++cg) oacc[rf][cg] = (f32x4)0.f;

    const unsigned short* Mh = mhi + (size_t)bf * 65536;
    const unsigned short* Ml = mlo + (size_t)bf * 65536;
    for (int kc = 0; kc < 8; ++kc) {
        bf16x8 ah[2], al[2];
#pragma unroll
        for (int rf = 0; rf < 2; ++rf) {
            int r = 32 * w + 16 * rf + m;
            ah[rf] = *(const bf16x8*)(Mh + r * 256 + 32 * kc + 8 * g);
            al[rf] = *(const bf16x8*)(Ml + r * 256 + 32 * kc + 8 * g);
        }
        bf16x8 bh[4], bl[4];
#pragma unroll
        for (int cg = 0; cg < 4; ++cg) {
            int n = 16 * cg + m;
            int off = (n * 512 + (32 * kc + 8 * g) * 2) ^ ((n & 7) << 4);
            bh[cg] = *(const bf16x8*)(L0 + off);
            bl[cg] = *(const bf16x8*)(L1 + off);
        }
#pragma unroll
        for (int rf = 0; rf < 2; ++rf)
#pragma unroll
            for (int cg = 0; cg < 4; ++cg) {
                oacc[rf][cg] = MFMA16(ah[rf], bh[cg], oacc[rf][cg]);
                oacc[rf][cg] = MFMA16(ah[rf], bl[cg], oacc[rf][cg]);
                oacc[rf][cg] = MFMA16(al[rf], bh[cg], oacc[rf][cg]);
            }
    }

    // ---- epilogue: + bias, direct stores ----
#pragma unroll
    for (int rf = 0; rf < 2; ++rf) {
        float bb[4];
#pragma unroll
        for (int r = 0; r < 4; ++r) bb[r] = bout[32 * w + 16 * rf + 4 * g + r];
#pragma unroll
        for (int cg = 0; cg < 4; ++cg) {
            int n = n0 + 16 * cg + m;
#pragma unroll
            for (int r = 0; r < 4; ++r) {
                int o = 32 * w + 16 * rf + 4 * g + r;
                og[(size_t)o * FN + n] = oacc[rf][cg][r] + bb[r];
            }
        }
    }
}

extern "C" void kernel_launch(void* const* d_in, const int* in_sizes, int n_in,
                              void* d_out, int out_size, void* d_ws, size_t ws_size,
                              hipStream_t stream) {
    const float* x    = (const float*)d_in[0];
    const float* wqkv = (const float*)d_in[1];
    const float* wout = (const float*)d_in[2];
    const float* bout = (const float*)d_in[3];
    float* out = (float*)d_out;
    float* ws  = (float*)d_ws;

    float* partC = ws + PARTC_OFF;
    float* partz = ws + PARTZ_OFF;
    unsigned short* U = (unsigned short*)(ws + USH_OFF);
    unsigned short* wqhi  = U + WQHI_O;
    unsigned short* wqlo  = U + WQLO_O;
    unsigned short* wkvhi = U + WKVHI_O;
    unsigned short* wkvlo = U + WKVLO_O;
    unsigned short* Mhi   = U + MHI_O;
    unsigned short* Mlo   = U + MLO_O;

    k0_prep<<<768, 256, 0, stream>>>(wqkv, wqhi, wqlo, wkvhi, wkvlo);
    k1_mfma<<<dim3(NS, BF), 512, 0, stream>>>(x, wkvhi, wkvlo, partC, partz);
    k2_M<<<BF, 256, 0, stream>>>(partC, partz, wout, Mhi, Mlo);
    k3_mfma<<<dim3(NN / TN3, BF), 512, 0, stream>>>(x, wqhi, wqlo, Mhi, Mlo, bout, out);
}